// Round 2
// baseline (1091.736 us; speedup 1.0000x reference)
//
#include <hip/hip_runtime.h>

#define DEVI __device__ __forceinline__

typedef __attribute__((ext_vector_type(4))) float   f32x4;
typedef __attribute__((ext_vector_type(8))) short   short8;
typedef __attribute__((ext_vector_type(8))) unsigned short ushort8;

// ---------- bf16 helpers (bit-level, RNE) ----------
DEVI float bf2f(unsigned short u) {
    unsigned int x = ((unsigned int)u) << 16;
    float f; __builtin_memcpy(&f, &x, 4); return f;
}
DEVI unsigned short f2bf(float f) {
    unsigned int x; __builtin_memcpy(&x, &f, 4);
    unsigned int r = x + 0x7FFFu + ((x >> 16) & 1u);
    return (unsigned short)(r >> 16);
}

DEVI f32x4 mfma_bf16(short8 a, short8 b, f32x4 c) {
    return __builtin_amdgcn_mfma_f32_16x16x32_bf16(a, b, c, 0, 0, 0);
}

DEVI void gld_lds16(const void* g, void* l) {
    __builtin_amdgcn_global_load_lds(
        (const __attribute__((address_space(1))) void*)g,
        (__attribute__((address_space(3))) void*)l, 16, 0, 0);
}

// =====================================================================
// GEMM: C[m,n] = scale * sum_k A[m,k] * Bt[n,k]     (Bt is [N][K] row-major)
// A: [M][K], leading dim K.  Output bf16.  128x128 tile, 4 waves, BK=32.
// SRCF32: A,B are fp32 -> reg-stage + convert to bf16 into LDS.
// else:   A,B are bf16 -> global_load_lds (16B/lane).
// ACC:    C += result (bf16 read-modify-write).
// Batched over blockIdx.z via element strides sA,sB,sC.
// =====================================================================
template<int SRCF32, int ACC>
__global__ __launch_bounds__(256)
void gemm_bt(const void* __restrict__ Ap, const void* __restrict__ Bp,
             unsigned short* __restrict__ Cp,
             int M, int N, int K,
             long long sA, long long sB, long long sC,
             float scale)
{
    __shared__ unsigned short As[128][32];   // 8 KB
    __shared__ unsigned short Bs[128][32];   // 8 KB

    const int z    = blockIdx.z;
    const int tm   = blockIdx.x * 128;
    const int tn   = blockIdx.y * 128;
    const int t    = threadIdx.x;
    const int lane = t & 63, wave = t >> 6;
    const int wr   = wave >> 1, wc = wave & 1;      // wave 64x64 sub-tile
    const int lh   = lane & 15, lq = lane >> 4;     // frag row/col, k-group
    const int sr   = t >> 2;                        // staging row 0..63
    const int sc   = (t & 3) * 8;                   // staging col {0,8,16,24}

    f32x4 acc[4][4];
#pragma unroll
    for (int i = 0; i < 4; i++)
#pragma unroll
        for (int j = 0; j < 4; j++) acc[i][j] = f32x4{0.f, 0.f, 0.f, 0.f};

    for (int k0 = 0; k0 < K; k0 += 32) {
        if constexpr (SRCF32) {
            const float* A = (const float*)Ap + (size_t)z * sA;
            const float* B = (const float*)Bp + (size_t)z * sB;
#pragma unroll
            for (int p = 0; p < 2; p++) {
                int row = sr + p * 64;
                {
                    const float* s = A + (size_t)(tm + row) * K + k0 + sc;
                    f32x4 f0 = *(const f32x4*)s;
                    f32x4 f1 = *(const f32x4*)(s + 4);
                    ushort8 h;
#pragma unroll
                    for (int e = 0; e < 4; e++) { h[e] = f2bf(f0[e]); h[e + 4] = f2bf(f1[e]); }
                    *(ushort8*)&As[row][sc] = h;
                }
                {
                    const float* s = B + (size_t)(tn + row) * K + k0 + sc;
                    f32x4 f0 = *(const f32x4*)s;
                    f32x4 f1 = *(const f32x4*)(s + 4);
                    ushort8 h;
#pragma unroll
                    for (int e = 0; e < 4; e++) { h[e] = f2bf(f0[e]); h[e + 4] = f2bf(f1[e]); }
                    *(ushort8*)&Bs[row][sc] = h;
                }
            }
        } else {
            const unsigned short* A = (const unsigned short*)Ap + (size_t)z * sA;
            const unsigned short* B = (const unsigned short*)Bp + (size_t)z * sB;
#pragma unroll
            for (int p = 0; p < 2; p++) {
                int row = sr + p * 64;
                gld_lds16(A + (size_t)(tm + row) * K + k0 + sc, &As[row][sc]);
                gld_lds16(B + (size_t)(tn + row) * K + k0 + sc, &Bs[row][sc]);
            }
        }
        __syncthreads();

        short8 af[4], bfr[4];
#pragma unroll
        for (int i = 0; i < 4; i++) af[i]  = *(const short8*)&As[wr * 64 + i * 16 + lh][lq * 8];
#pragma unroll
        for (int j = 0; j < 4; j++) bfr[j] = *(const short8*)&Bs[wc * 64 + j * 16 + lh][lq * 8];
#pragma unroll
        for (int i = 0; i < 4; i++)
#pragma unroll
            for (int j = 0; j < 4; j++)
                acc[i][j] = mfma_bf16(af[i], bfr[j], acc[i][j]);
        __syncthreads();
    }

    // Epilogue: C/D frag layout col=lane&15, row=(lane>>4)*4+reg (m89-verified)
    unsigned short* C = Cp + (size_t)z * sC;
#pragma unroll
    for (int i = 0; i < 4; i++)
#pragma unroll
        for (int j = 0; j < 4; j++)
#pragma unroll
            for (int r = 0; r < 4; r++) {
                int m = tm + wr * 64 + i * 16 + lq * 4 + r;
                int n = tn + wc * 64 + j * 16 + lh;
                float v = acc[i][j][r] * scale;
                size_t idx = (size_t)m * N + n;
                if constexpr (ACC) C[idx] = f2bf(bf2f(C[idx]) + v);
                else               C[idx] = f2bf(v);
            }
}

// =====================================================================
// Row softmax, in place, bf16 rows of length 2048. One block per row.
// =====================================================================
__global__ __launch_bounds__(256)
void softmax_rows(unsigned short* __restrict__ P)
{
    const size_t row = blockIdx.x;
    unsigned short* p = P + row * 2048;
    const int t = threadIdx.x, lane = t & 63, wave = t >> 6;

    ushort8 u = *(const ushort8*)(p + t * 8);
    float v[8];
    float mx = -1e30f;
#pragma unroll
    for (int j = 0; j < 8; j++) { v[j] = bf2f(u[j]); mx = fmaxf(mx, v[j]); }
#pragma unroll
    for (int o = 32; o; o >>= 1) mx = fmaxf(mx, __shfl_xor(mx, o));

    __shared__ float red[8];
    if (lane == 0) red[wave] = mx;
    __syncthreads();
    mx = fmaxf(fmaxf(red[0], red[1]), fmaxf(red[2], red[3]));

    float s = 0.f;
#pragma unroll
    for (int j = 0; j < 8; j++) { v[j] = __expf(v[j] - mx); s += v[j]; }
#pragma unroll
    for (int o = 32; o; o >>= 1) s += __shfl_xor(s, o);
    if (lane == 0) red[4 + wave] = s;
    __syncthreads();
    float inv = 1.0f / (red[4] + red[5] + red[6] + red[7]);

    ushort8 o8;
#pragma unroll
    for (int j = 0; j < 8; j++) o8[j] = f2bf(v[j] * inv);
    *(ushort8*)(p + t * 8) = o8;
}

// =====================================================================
// x = 0.5*outs(bf16) + main_f(fp32); LayerNorm(x); partial max over 64 rows.
// Block: 256 thr = 4 waves; wave handles 16 rows (1 wave-reduce per row).
// grid.x = B * (2048/64) = 256.  partial: [B][32][1024] fp32.
// =====================================================================
__global__ __launch_bounds__(256)
void ln_max_partial(const unsigned short* __restrict__ outs,
                    const float* __restrict__ mainf,
                    const float* __restrict__ gamma,
                    const float* __restrict__ beta,
                    float* __restrict__ partial)
{
    const int bx = blockIdx.x;
    const int b = bx >> 5, rc = bx & 31;
    const int t = threadIdx.x, lane = t & 63, wave = t >> 6;

    float g[16], be[16];
#pragma unroll
    for (int j = 0; j < 16; j++) { int d = j * 64 + lane; g[j] = gamma[d]; be[j] = beta[d]; }

    float rmax[16];
#pragma unroll
    for (int j = 0; j < 16; j++) rmax[j] = -1e30f;

    for (int rr = 0; rr < 16; rr++) {
        int l = rc * 64 + wave * 16 + rr;
        size_t base = ((size_t)b * 2048 + l) * 1024;
        float x[16], s = 0.f, s2 = 0.f;
#pragma unroll
        for (int j = 0; j < 16; j++) {
            int d = j * 64 + lane;
            float xv = 0.5f * bf2f(outs[base + d]) + mainf[base + d];
            x[j] = xv; s += xv; s2 += xv * xv;
        }
#pragma unroll
        for (int o = 32; o; o >>= 1) { s += __shfl_xor(s, o); s2 += __shfl_xor(s2, o); }
        float mu   = s * (1.f / 1024.f);
        float var  = s2 * (1.f / 1024.f) - mu * mu;
        float rstd = rsqrtf(var + 1e-5f);
#pragma unroll
        for (int j = 0; j < 16; j++) {
            float f = (x[j] - mu) * rstd * g[j] + be[j];
            rmax[j] = fmaxf(rmax[j], f);
        }
    }

    __shared__ float sm[4][1024];   // 16 KB
#pragma unroll
    for (int j = 0; j < 16; j++) sm[wave][j * 64 + lane] = rmax[j];
    __syncthreads();
    for (int d = t; d < 1024; d += 256) {
        float m = fmaxf(fmaxf(sm[0][d], sm[1][d]), fmaxf(sm[2][d], sm[3][d]));
        partial[((size_t)b * 32 + rc) * 1024 + d] = m;
    }
}

__global__ __launch_bounds__(256)
void reduce_max_final(const float* __restrict__ partial, float* __restrict__ out)
{
    int i = blockIdx.x * 256 + threadIdx.x;
    if (i >= 8192) return;
    int b = i >> 10, d = i & 1023;
    const float* p = partial + (size_t)b * 32 * 1024 + d;
    float m = -1e30f;
#pragma unroll
    for (int rc = 0; rc < 32; rc++) m = fmaxf(m, p[(size_t)rc * 1024]);
    out[i] = m;
}

// Diagnostic: if ws too small, absmax error ~= ws_size tells us the real size.
__global__ void ws_report(float* out, float v)
{
    int i = blockIdx.x * 256 + threadIdx.x;
    if (i < 8192) out[i] = v;
}

// =====================================================================
extern "C" void kernel_launch(void* const* d_in, const int* in_sizes, int n_in,
                              void* d_out, int out_size, void* d_ws, size_t ws_size,
                              hipStream_t stream)
{
    const float* mainf = (const float*)d_in[0];
    const float* cof1  = (const float*)d_in[1];
    const float* cof2  = (const float*)d_in[2];
    const float* Wq    = (const float*)d_in[3];
    const float* Wk1   = (const float*)d_in[4];
    const float* Wk2   = (const float*)d_in[5];
    const float* Wv1   = (const float*)d_in[6];
    const float* Wv2   = (const float*)d_in[7];
    const float* gamma = (const float*)d_in[8];
    const float* beta  = (const float*)d_in[9];
    float* out = (float*)d_out;

    const size_t NEED = 256ull << 20;   // exactly 256 MiB (ws_size == 268435456)
    if (ws_size < NEED) {
        ws_report<<<dim3(32), dim3(256), 0, stream>>>(out, (float)ws_size);
        return;
    }

    char* ws = (char*)d_ws;
    unsigned short* q    = (unsigned short*)(ws);                   // 32 MiB
    unsigned short* k1   = (unsigned short*)(ws + (32ull  << 20));  // 32 MiB
    unsigned short* k2   = (unsigned short*)(ws + (64ull  << 20));  // 32 MiB
    unsigned short* v1t  = (unsigned short*)(ws + (96ull  << 20));  // [B][1024][2048]
    unsigned short* v2t  = (unsigned short*)(ws + (128ull << 20));
    unsigned short* P    = (unsigned short*)(ws + (160ull << 20));  // [B][2048][2048] 64 MiB
    unsigned short* outs = (unsigned short*)(ws + (224ull << 20));  // [B][2048][1024] 32 MiB
    // part ALIASES q (q is dead after the 2nd QK^T GEMM, before ln_max_partial)
    float*          part = (float*)(ws);                            // [B][32][1024] 1 MiB

    dim3 blk(256);
    const long long LD = 2097152;   // L*D = 2048*1024
    const long long LL = 4194304;   // L*L
    const float qk_scale = 0.03125f; // 1/sqrt(1024)

    // ---- projections (fp32 inputs, reg-stage+convert) ----
    // q[m,e]  = sum_d main[m,d]  Wq[e,d]      (m = b*2048+l, flat)
    gemm_bt<1, 0><<<dim3(128, 8, 1), blk, 0, stream>>>(mainf, Wq,  q,  16384, 1024, 1024, 0, 0, 0, 1.0f);
    gemm_bt<1, 0><<<dim3(128, 8, 1), blk, 0, stream>>>(cof1,  Wk1, k1, 16384, 1024, 1024, 0, 0, 0, 1.0f);
    gemm_bt<1, 0><<<dim3(128, 8, 1), blk, 0, stream>>>(cof2,  Wk2, k2, 16384, 1024, 1024, 0, 0, 0, 1.0f);
    // vt[b][e][l] = sum_d Wv[e,d] co[b,l,d]   (pre-transposed V: A=W, Bt=co_b)
    gemm_bt<1, 0><<<dim3(8, 16, 8), blk, 0, stream>>>(Wv1, cof1, v1t, 1024, 2048, 1024, 0, LD, LD, 1.0f);
    gemm_bt<1, 0><<<dim3(8, 16, 8), blk, 0, stream>>>(Wv2, cof2, v2t, 1024, 2048, 1024, 0, LD, LD, 1.0f);

    // ---- path 1 ----
    gemm_bt<0, 0><<<dim3(16, 16, 8), blk, 0, stream>>>(q, k1, P, 2048, 2048, 1024, LD, LD, LL, qk_scale);
    softmax_rows<<<dim3(16384), blk, 0, stream>>>(P);
    gemm_bt<0, 0><<<dim3(16, 8, 8),  blk, 0, stream>>>(P, v1t, outs, 2048, 1024, 2048, LL, LD, LD, 1.0f);

    // ---- path 2 (P buffer reused; outs accumulated) ----
    gemm_bt<0, 0><<<dim3(16, 16, 8), blk, 0, stream>>>(q, k2, P, 2048, 2048, 1024, LD, LD, LL, qk_scale);
    softmax_rows<<<dim3(16384), blk, 0, stream>>>(P);
    gemm_bt<0, 1><<<dim3(16, 8, 8),  blk, 0, stream>>>(P, v2t, outs, 2048, 1024, 2048, LL, LD, LD, 1.0f);

    // ---- residual + LN + max over sequence (part aliases dead q) ----
    ln_max_partial<<<dim3(256), blk, 0, stream>>>(outs, mainf, gamma, beta, part);
    reduce_max_final<<<dim3(32), blk, 0, stream>>>(part, out);
}

// Round 3
// 1041.627 us; speedup vs baseline: 1.0481x; 1.0481x over previous
//
#include <hip/hip_runtime.h>

#define DEVI __device__ __forceinline__

typedef __attribute__((ext_vector_type(4))) float   f32x4;
typedef __attribute__((ext_vector_type(8))) short   short8;
typedef __attribute__((ext_vector_type(8))) unsigned short ushort8;

// ---------- bf16 helpers (bit-level, RNE) ----------
DEVI float bf2f(unsigned short u) {
    unsigned int x = ((unsigned int)u) << 16;
    float f; __builtin_memcpy(&f, &x, 4); return f;
}
DEVI unsigned short f2bf(float f) {
    unsigned int x; __builtin_memcpy(&x, &f, 4);
    unsigned int r = x + 0x7FFFu + ((x >> 16) & 1u);
    return (unsigned short)(r >> 16);
}

DEVI f32x4 mfma_bf16(short8 a, short8 b, f32x4 c) {
    return __builtin_amdgcn_mfma_f32_16x16x32_bf16(a, b, c, 0, 0, 0);
}

DEVI void gld_lds16(const void* g, void* l) {
    __builtin_amdgcn_global_load_lds(
        (const __attribute__((address_space(1))) void*)g,
        (__attribute__((address_space(3))) void*)l, 16, 0, 0);
}

// =====================================================================
// fp32 -> bf16 bulk convert: 3 tensors of 16777216 elems each.
// out is contiguous: [tensor][16777216]. grid=(2048,3), 256 thr.
// =====================================================================
__global__ __launch_bounds__(256)
void conv3_f32_bf16(const float* __restrict__ a, const float* __restrict__ b,
                    const float* __restrict__ c, unsigned short* __restrict__ o)
{
    const float* src = (blockIdx.y == 0) ? a : (blockIdx.y == 1 ? b : c);
    unsigned short* dst = o + (size_t)blockIdx.y * 16777216ull;
    const size_t step = (size_t)gridDim.x * 256 * 8;
    for (size_t i = ((size_t)blockIdx.x * 256 + threadIdx.x) * 8; i < 16777216ull; i += step) {
        f32x4 f0 = *(const f32x4*)(src + i);
        f32x4 f1 = *(const f32x4*)(src + i + 4);
        ushort8 h;
#pragma unroll
        for (int e = 0; e < 4; e++) { h[e] = f2bf(f0[e]); h[e + 4] = f2bf(f1[e]); }
        *(ushort8*)(dst + i) = h;
    }
}

// =====================================================================
// GEMM: C[m,n] = scale * sum_k A[m,k] * Bt[n,k]     (Bt is [N][K] row-major)
// Output bf16.  128x128 tile, 4 waves, BK=32.
// SRCA32/SRCB32: that operand is fp32 -> reg-stage + convert to bf16 LDS;
//                else bf16 -> global_load_lds (16B/lane, linear dest).
// ACC: C += result (bf16 RMW).  Batched over blockIdx.z (elem strides).
// =====================================================================
template<int SRCA32, int SRCB32, int ACC>
__global__ __launch_bounds__(256)
void gemm_bt(const void* __restrict__ Ap, const void* __restrict__ Bp,
             unsigned short* __restrict__ Cp,
             int M, int N, int K,
             long long sA, long long sB, long long sC,
             float scale)
{
    __shared__ unsigned short As[128][32];   // 8 KB
    __shared__ unsigned short Bs[128][32];   // 8 KB

    const int z    = blockIdx.z;
    const int tm   = blockIdx.x * 128;
    const int tn   = blockIdx.y * 128;
    const int t    = threadIdx.x;
    const int lane = t & 63, wave = t >> 6;
    const int wr   = wave >> 1, wc = wave & 1;      // wave 64x64 sub-tile
    const int lh   = lane & 15, lq = lane >> 4;     // frag row, k-group
    const int sr   = t >> 2;                        // staging row 0..63
    const int sc   = (t & 3) * 8;                   // staging col {0,8,16,24}

    f32x4 acc[4][4];
#pragma unroll
    for (int i = 0; i < 4; i++)
#pragma unroll
        for (int j = 0; j < 4; j++) acc[i][j] = f32x4{0.f, 0.f, 0.f, 0.f};

    for (int k0 = 0; k0 < K; k0 += 32) {
        // ---- stage A tile ----
        if constexpr (SRCA32) {
            const float* A = (const float*)Ap + (size_t)z * sA;
#pragma unroll
            for (int p = 0; p < 2; p++) {
                int row = sr + p * 64;
                const float* s = A + (size_t)(tm + row) * K + k0 + sc;
                f32x4 f0 = *(const f32x4*)s;
                f32x4 f1 = *(const f32x4*)(s + 4);
                ushort8 h;
#pragma unroll
                for (int e = 0; e < 4; e++) { h[e] = f2bf(f0[e]); h[e + 4] = f2bf(f1[e]); }
                *(ushort8*)&As[row][sc] = h;
            }
        } else {
            const unsigned short* A = (const unsigned short*)Ap + (size_t)z * sA;
#pragma unroll
            for (int p = 0; p < 2; p++) {
                int row = sr + p * 64;
                gld_lds16(A + (size_t)(tm + row) * K + k0 + sc, &As[row][sc]);
            }
        }
        // ---- stage B tile ----
        if constexpr (SRCB32) {
            const float* B = (const float*)Bp + (size_t)z * sB;
#pragma unroll
            for (int p = 0; p < 2; p++) {
                int row = sr + p * 64;
                const float* s = B + (size_t)(tn + row) * K + k0 + sc;
                f32x4 f0 = *(const f32x4*)s;
                f32x4 f1 = *(const f32x4*)(s + 4);
                ushort8 h;
#pragma unroll
                for (int e = 0; e < 4; e++) { h[e] = f2bf(f0[e]); h[e + 4] = f2bf(f1[e]); }
                *(ushort8*)&Bs[row][sc] = h;
            }
        } else {
            const unsigned short* B = (const unsigned short*)Bp + (size_t)z * sB;
#pragma unroll
            for (int p = 0; p < 2; p++) {
                int row = sr + p * 64;
                gld_lds16(B + (size_t)(tn + row) * K + k0 + sc, &Bs[row][sc]);
            }
        }
        __syncthreads();

        short8 af[4], bfr[4];
#pragma unroll
        for (int i = 0; i < 4; i++) af[i]  = *(const short8*)&As[wr * 64 + i * 16 + lh][lq * 8];
#pragma unroll
        for (int j = 0; j < 4; j++) bfr[j] = *(const short8*)&Bs[wc * 64 + j * 16 + lh][lq * 8];
#pragma unroll
        for (int i = 0; i < 4; i++)
#pragma unroll
            for (int j = 0; j < 4; j++)
                acc[i][j] = mfma_bf16(af[i], bfr[j], acc[i][j]);
        __syncthreads();
    }

    // Epilogue: C/D frag layout col=lane&15, row=(lane>>4)*4+reg (m89-verified)
    unsigned short* C = Cp + (size_t)z * sC;
#pragma unroll
    for (int i = 0; i < 4; i++)
#pragma unroll
        for (int j = 0; j < 4; j++)
#pragma unroll
            for (int r = 0; r < 4; r++) {
                int m = tm + wr * 64 + i * 16 + lq * 4 + r;
                int n = tn + wc * 64 + j * 16 + lh;
                float v = acc[i][j][r] * scale;
                size_t idx = (size_t)m * N + n;
                if constexpr (ACC) C[idx] = f2bf(bf2f(C[idx]) + v);
                else               C[idx] = f2bf(v);
            }
}

// =====================================================================
// Row softmax, in place, bf16 rows of length 2048. One block per row.
// =====================================================================
__global__ __launch_bounds__(256)
void softmax_rows(unsigned short* __restrict__ P)
{
    const size_t row = blockIdx.x;
    unsigned short* p = P + row * 2048;
    const int t = threadIdx.x, lane = t & 63, wave = t >> 6;

    ushort8 u = *(const ushort8*)(p + t * 8);
    float v[8];
    float mx = -1e30f;
#pragma unroll
    for (int j = 0; j < 8; j++) { v[j] = bf2f(u[j]); mx = fmaxf(mx, v[j]); }
#pragma unroll
    for (int o = 32; o; o >>= 1) mx = fmaxf(mx, __shfl_xor(mx, o));

    __shared__ float red[8];
    if (lane == 0) red[wave] = mx;
    __syncthreads();
    mx = fmaxf(fmaxf(red[0], red[1]), fmaxf(red[2], red[3]));

    float s = 0.f;
#pragma unroll
    for (int j = 0; j < 8; j++) { v[j] = __expf(v[j] - mx); s += v[j]; }
#pragma unroll
    for (int o = 32; o; o >>= 1) s += __shfl_xor(s, o);
    if (lane == 0) red[4 + wave] = s;
    __syncthreads();
    float inv = 1.0f / (red[4] + red[5] + red[6] + red[7]);

    ushort8 o8;
#pragma unroll
    for (int j = 0; j < 8; j++) o8[j] = f2bf(v[j] * inv);
    *(ushort8*)(p + t * 8) = o8;
}

// =====================================================================
// x = 0.5*outs(bf16) + main_f(fp32); LayerNorm(x); partial max over 64 rows.
// grid.x = B * (2048/64) = 256.  partial: [B][32][1024] fp32.
// =====================================================================
__global__ __launch_bounds__(256)
void ln_max_partial(const unsigned short* __restrict__ outs,
                    const float* __restrict__ mainf,
                    const float* __restrict__ gamma,
                    const float* __restrict__ beta,
                    float* __restrict__ partial)
{
    const int bx = blockIdx.x;
    const int b = bx >> 5, rc = bx & 31;
    const int t = threadIdx.x, lane = t & 63, wave = t >> 6;

    float g[16], be[16];
#pragma unroll
    for (int j = 0; j < 16; j++) { int d = j * 64 + lane; g[j] = gamma[d]; be[j] = beta[d]; }

    float rmax[16];
#pragma unroll
    for (int j = 0; j < 16; j++) rmax[j] = -1e30f;

    for (int rr = 0; rr < 16; rr++) {
        int l = rc * 64 + wave * 16 + rr;
        size_t base = ((size_t)b * 2048 + l) * 1024;
        float x[16], s = 0.f, s2 = 0.f;
#pragma unroll
        for (int j = 0; j < 16; j++) {
            int d = j * 64 + lane;
            float xv = 0.5f * bf2f(outs[base + d]) + mainf[base + d];
            x[j] = xv; s += xv; s2 += xv * xv;
        }
#pragma unroll
        for (int o = 32; o; o >>= 1) { s += __shfl_xor(s, o); s2 += __shfl_xor(s2, o); }
        float mu   = s * (1.f / 1024.f);
        float var  = s2 * (1.f / 1024.f) - mu * mu;
        float rstd = rsqrtf(var + 1e-5f);
#pragma unroll
        for (int j = 0; j < 16; j++) {
            float f = (x[j] - mu) * rstd * g[j] + be[j];
            rmax[j] = fmaxf(rmax[j], f);
        }
    }

    __shared__ float sm[4][1024];   // 16 KB
#pragma unroll
    for (int j = 0; j < 16; j++) sm[wave][j * 64 + lane] = rmax[j];
    __syncthreads();
    for (int d = t; d < 1024; d += 256) {
        float m = fmaxf(fmaxf(sm[0][d], sm[1][d]), fmaxf(sm[2][d], sm[3][d]));
        partial[((size_t)b * 32 + rc) * 1024 + d] = m;
    }
}

__global__ __launch_bounds__(256)
void reduce_max_final(const float* __restrict__ partial, float* __restrict__ out)
{
    int i = blockIdx.x * 256 + threadIdx.x;
    if (i >= 8192) return;
    int b = i >> 10, d = i & 1023;
    const float* p = partial + (size_t)b * 32 * 1024 + d;
    float m = -1e30f;
#pragma unroll
    for (int rc = 0; rc < 32; rc++) m = fmaxf(m, p[(size_t)rc * 1024]);
    out[i] = m;
}

// Diagnostic: if ws too small, absmax error ~= ws_size tells us the real size.
__global__ void ws_report(float* out, float v)
{
    int i = blockIdx.x * 256 + threadIdx.x;
    if (i < 8192) out[i] = v;
}

// =====================================================================
extern "C" void kernel_launch(void* const* d_in, const int* in_sizes, int n_in,
                              void* d_out, int out_size, void* d_ws, size_t ws_size,
                              hipStream_t stream)
{
    const float* mainf = (const float*)d_in[0];
    const float* cof1  = (const float*)d_in[1];
    const float* cof2  = (const float*)d_in[2];
    const float* Wq    = (const float*)d_in[3];
    const float* Wk1   = (const float*)d_in[4];
    const float* Wk2   = (const float*)d_in[5];
    const float* Wv1   = (const float*)d_in[6];
    const float* Wv2   = (const float*)d_in[7];
    const float* gamma = (const float*)d_in[8];
    const float* beta  = (const float*)d_in[9];
    float* out = (float*)d_out;

    const size_t NEED = 256ull << 20;
    if (ws_size < NEED) {
        ws_report<<<dim3(32), dim3(256), 0, stream>>>(out, (float)ws_size);
        return;
    }

    // ---- workspace plan (exactly 256 MiB, with aliasing) ----
    // 0   -32  : mainb  -> k2 (after q) -> part (1 MiB, after QK2)
    // 32  -64  : co1b   -> v2t (after v1t/k1)
    // 64  -96  : co2b   -> outs (after v2t/k2)
    // 96  -128 : q
    // 128 -160 : k1
    // 160 -192 : v1t
    // 192 -256 : P (64 MiB)
    char* ws = (char*)d_ws;
    unsigned short* mainb = (unsigned short*)(ws);
    unsigned short* co1b  = (unsigned short*)(ws + (32ull  << 20));
    unsigned short* co2b  = (unsigned short*)(ws + (64ull  << 20));
    unsigned short* q     = (unsigned short*)(ws + (96ull  << 20));
    unsigned short* k1    = (unsigned short*)(ws + (128ull << 20));
    unsigned short* v1t   = (unsigned short*)(ws + (160ull << 20));
    unsigned short* P     = (unsigned short*)(ws + (192ull << 20));
    unsigned short* k2    = mainb;                    // alias (mainb dead after q)
    unsigned short* v2t   = co1b;                     // alias (co1b dead after v1t)
    unsigned short* outs  = co2b;                     // alias (co2b dead after k2)
    float*          part  = (float*)(ws);             // alias (k2 dead after QK2)

    dim3 blk(256);
    const long long LD = 2097152;    // L*D = 2048*1024
    const long long LL = 4194304;    // L*L
    const float qk_scale = 0.03125f; // 1/sqrt(1024)

    // ---- fp32 -> bf16 bulk convert (mainb, co1b, co2b contiguous) ----
    conv3_f32_bf16<<<dim3(2048, 3), blk, 0, stream>>>(mainf, cof1, cof2, mainb);

    // ---- projections: A bf16 (gld_lds), B = weight fp32 (reg-staged) ----
    gemm_bt<0, 1, 0><<<dim3(128, 8, 1), blk, 0, stream>>>(mainb, Wq,  q,  16384, 1024, 1024, 0, 0, 0, 1.0f);
    gemm_bt<0, 1, 0><<<dim3(128, 8, 1), blk, 0, stream>>>(co1b,  Wk1, k1, 16384, 1024, 1024, 0, 0, 0, 1.0f);
    // vt[b][e][l] = sum_d Wv[e,d] co[b,l,d]  (A = W fp32, Bt = co bf16)
    gemm_bt<1, 0, 0><<<dim3(8, 16, 8), blk, 0, stream>>>(Wv1, co1b, v1t, 1024, 2048, 1024, 0, LD, LD, 1.0f);
    gemm_bt<1, 0, 0><<<dim3(8, 16, 8), blk, 0, stream>>>(Wv2, co2b, v2t, 1024, 2048, 1024, 0, LD, LD, 1.0f);
    gemm_bt<0, 1, 0><<<dim3(128, 8, 1), blk, 0, stream>>>(co2b,  Wk2, k2, 16384, 1024, 1024, 0, 0, 0, 1.0f);

    // ---- path 1 ----
    gemm_bt<0, 0, 0><<<dim3(16, 16, 8), blk, 0, stream>>>(q, k1, P, 2048, 2048, 1024, LD, LD, LL, qk_scale);
    softmax_rows<<<dim3(16384), blk, 0, stream>>>(P);
    gemm_bt<0, 0, 0><<<dim3(16, 8, 8),  blk, 0, stream>>>(P, v1t, outs, 2048, 1024, 2048, LL, LD, LD, 1.0f);

    // ---- path 2 (P reused; outs accumulated) ----
    gemm_bt<0, 0, 0><<<dim3(16, 16, 8), blk, 0, stream>>>(q, k2, P, 2048, 2048, 1024, LD, LD, LL, qk_scale);
    softmax_rows<<<dim3(16384), blk, 0, stream>>>(P);
    gemm_bt<0, 0, 1><<<dim3(16, 8, 8),  blk, 0, stream>>>(P, v2t, outs, 2048, 1024, 2048, LL, LD, LD, 1.0f);

    // ---- residual + LN + max over sequence ----
    ln_max_partial<<<dim3(256), blk, 0, stream>>>(outs, mainf, gamma, beta, part);
    reduce_max_final<<<dim3(32), blk, 0, stream>>>(part, out);
}

// Round 4
// 784.373 us; speedup vs baseline: 1.3919x; 1.3280x over previous
//
#include <hip/hip_runtime.h>

#define DEVI __device__ __forceinline__

typedef __attribute__((ext_vector_type(4))) float   f32x4;
typedef __attribute__((ext_vector_type(8))) short   short8;
typedef __attribute__((ext_vector_type(8))) unsigned short ushort8;

// ---------- bf16 helpers (bit-level, RNE) ----------
DEVI float bf2f(unsigned short u) {
    unsigned int x = ((unsigned int)u) << 16;
    float f; __builtin_memcpy(&f, &x, 4); return f;
}
DEVI unsigned short f2bf(float f) {
    unsigned int x; __builtin_memcpy(&x, &f, 4);
    unsigned int r = x + 0x7FFFu + ((x >> 16) & 1u);
    return (unsigned short)(r >> 16);
}

DEVI f32x4 mfma_bf16(short8 a, short8 b, f32x4 c) {
    return __builtin_amdgcn_mfma_f32_16x16x32_bf16(a, b, c, 0, 0, 0);
}

DEVI void gld_lds16(const void* g, void* l) {
    __builtin_amdgcn_global_load_lds(
        (const __attribute__((address_space(1))) void*)g,
        (__attribute__((address_space(3))) void*)l, 16, 0, 0);
}

// =====================================================================
// fp32 -> bf16 bulk convert: 3 tensors of 16777216 elems each.
// =====================================================================
__global__ __launch_bounds__(256)
void conv3_f32_bf16(const float* __restrict__ a, const float* __restrict__ b,
                    const float* __restrict__ c, unsigned short* __restrict__ o)
{
    const float* src = (blockIdx.y == 0) ? a : (blockIdx.y == 1 ? b : c);
    unsigned short* dst = o + (size_t)blockIdx.y * 16777216ull;
    const size_t step = (size_t)gridDim.x * 256 * 8;
    for (size_t i = ((size_t)blockIdx.x * 256 + threadIdx.x) * 8; i < 16777216ull; i += step) {
        f32x4 f0 = *(const f32x4*)(src + i);
        f32x4 f1 = *(const f32x4*)(src + i + 4);
        ushort8 h;
#pragma unroll
        for (int e = 0; e < 4; e++) { h[e] = f2bf(f0[e]); h[e + 4] = f2bf(f1[e]); }
        *(ushort8*)(dst + i) = h;
    }
}

// =====================================================================
// GEMM 256x256 tile, BK=64, 8 waves (2Mx4N), 2-phase LDS double-buffer.
// C[m,n] = scale * sum_k A[m,k]*Bt[n,k].  Bt is [N][K] row-major.
// LDS layout: tile[row][64] bf16 (128B rows), T2 swizzle slot^=(row&7)
//   bf16 operand: gld_lds (linear dest) + pre-swizzled GLOBAL source
//   fp32 operand: reg-stage (loads early / convert+ds_write late), swizzled dest
// Block swizzle: bijective XCD chunk + group-M supergroups (A-slab locality).
// =====================================================================
template<int SRCA32, int SRCB32, int ACC>
__global__ __launch_bounds__(512, 2)
void gemm256(const void* __restrict__ Ap, const void* __restrict__ Bp,
             unsigned short* __restrict__ Cp,
             int N, int K, long long sA, long long sB, long long sC,
             float scale, int nbx, int nby, int nwg_z)
{
    __shared__ unsigned short As[2][256][64];   // 64 KB
    __shared__ unsigned short Bs[2][256][64];   // 64 KB

    const int t    = threadIdx.x;
    const int lane = t & 63, wave = t >> 6;
    const int wr   = wave >> 2, wc = wave & 3;   // 2 x 4 wave grid
    const int lh   = lane & 15, lq = lane >> 4;
    const int l8   = lh & 7;

    // ---- block swizzle: XCD bijective chunk, then group-M ----
    const int total = (int)gridDim.x;            // always % 8 == 0 here
    const int lid   = blockIdx.x;
    const int q0    = total >> 3;
    const int swz   = (lid & 7) * q0 + (lid >> 3);
    const int z     = swz / nwg_z;
    const int id2   = swz - z * nwg_z;
    const int GRP   = 8;
    const int gsz   = GRP * nby;
    const int grp   = id2 / gsz, loc = id2 - grp * gsz;
    int gm = nbx - grp * GRP; gm = (gm > GRP) ? GRP : gm;
    const int bx = grp * GRP + loc % gm;
    const int by = loc / gm;
    const int tm = bx << 8, tn = by << 8;

    // staging geometry: granule = 16B; row = p*64 + (t>>3), slot = t&7
    const int srow  = t >> 3;        // 0..63
    const int sslot = t & 7;
    const int rsw   = srow & 7;

    const unsigned short* Ab = nullptr; const float* Af = nullptr;
    const unsigned short* Bb = nullptr; const float* Bf = nullptr;
    if constexpr (SRCA32) Af = (const float*)Ap + (size_t)z * sA;
    else                  Ab = (const unsigned short*)Ap + (size_t)z * sA;
    if constexpr (SRCB32) Bf = (const float*)Bp + (size_t)z * sB;
    else                  Bb = (const unsigned short*)Bp + (size_t)z * sB;

    f32x4 acc[8][4];
#pragma unroll
    for (int i = 0; i < 8; i++)
#pragma unroll
        for (int j = 0; j < 4; j++) acc[i][j] = f32x4{0.f, 0.f, 0.f, 0.f};

    const int NT = K >> 6;

    // ---- staging helpers ----
    auto issueA = [&](int b, int k0) {
        if constexpr (!SRCA32) {
#pragma unroll
            for (int p = 0; p < 4; p++) {
                int row = p * 64 + srow;
                gld_lds16(Ab + (size_t)(tm + row) * K + k0 + ((sslot ^ rsw) << 3),
                          &As[b][row][sslot << 3]);
            }
        }
    };
    auto issueB = [&](int b, int k0) {
        if constexpr (!SRCB32) {
#pragma unroll
            for (int p = 0; p < 4; p++) {
                int row = p * 64 + srow;
                gld_lds16(Bb + (size_t)(tn + row) * K + k0 + ((sslot ^ rsw) << 3),
                          &Bs[b][row][sslot << 3]);
            }
        }
    };
    auto loadAf = [&](f32x4* fr, int k0) {
        if constexpr (SRCA32) {
#pragma unroll
            for (int p = 0; p < 4; p++) {
                const float* s = Af + (size_t)(tm + p * 64 + srow) * K + k0 + (sslot << 3);
                fr[2 * p]     = *(const f32x4*)s;
                fr[2 * p + 1] = *(const f32x4*)(s + 4);
            }
        }
    };
    auto loadBf = [&](f32x4* fr, int k0) {
        if constexpr (SRCB32) {
#pragma unroll
            for (int p = 0; p < 4; p++) {
                const float* s = Bf + (size_t)(tn + p * 64 + srow) * K + k0 + (sslot << 3);
                fr[2 * p]     = *(const f32x4*)s;
                fr[2 * p + 1] = *(const f32x4*)(s + 4);
            }
        }
    };
    auto storeAf = [&](const f32x4* fr, int b) {
        if constexpr (SRCA32) {
#pragma unroll
            for (int p = 0; p < 4; p++) {
                int row = p * 64 + srow;
                ushort8 h;
#pragma unroll
                for (int e = 0; e < 4; e++) { h[e] = f2bf(fr[2*p][e]); h[e+4] = f2bf(fr[2*p+1][e]); }
                *(ushort8*)&As[b][row][(sslot ^ rsw) << 3] = h;
            }
        }
    };
    auto storeBf = [&](const f32x4* fr, int b) {
        if constexpr (SRCB32) {
#pragma unroll
            for (int p = 0; p < 4; p++) {
                int row = p * 64 + srow;
                ushort8 h;
#pragma unroll
                for (int e = 0; e < 4; e++) { h[e] = f2bf(fr[2*p][e]); h[e+4] = f2bf(fr[2*p+1][e]); }
                *(ushort8*)&Bs[b][row][(sslot ^ rsw) << 3] = h;
            }
        }
    };

    // ---- prologue: stage tile 0 into buf 0 ----
    issueA(0, 0); issueB(0, 0);
    {
        f32x4 fr[8];
        if constexpr (SRCA32) { loadAf(fr, 0); storeAf(fr, 0); }
        if constexpr (SRCB32) { loadBf(fr, 0); storeBf(fr, 0); }
    }
    __syncthreads();

    int cur = 0;
    for (int kt = 0; kt < NT; kt++) {
        f32x4 fra[8], frb[8];
        const int  kn = (kt + 1) << 6;
        const bool pf = (kt + 1 < NT);
        if (pf) {
            issueA(cur ^ 1, kn); issueB(cur ^ 1, kn);
            loadAf(fra, kn);     loadBf(frb, kn);
        }

        // ---- compute tile cur: 2 kk-halves x 32 MFMA ----
#pragma unroll
        for (int kk = 0; kk < 2; kk++) {
            short8 af[8], bq[4];
#pragma unroll
            for (int i = 0; i < 8; i++) {
                int row = wr * 128 + i * 16 + lh;
                af[i] = *(const short8*)&As[cur][row][(((kk << 2) | lq) ^ l8) << 3];
            }
#pragma unroll
            for (int j = 0; j < 4; j++) {
                int row = wc * 64 + j * 16 + lh;
                bq[j] = *(const short8*)&Bs[cur][row][(((kk << 2) | lq) ^ l8) << 3];
            }
#pragma unroll
            for (int i = 0; i < 8; i++)
#pragma unroll
                for (int j = 0; j < 4; j++)
                    acc[i][j] = mfma_bf16(af[i], bq[j], acc[i][j]);
        }

        if (pf) { storeAf(fra, cur ^ 1); storeBf(frb, cur ^ 1); }
        __syncthreads();
        cur ^= 1;
    }

    // ---- epilogue: C/D frag col=lane&15, row=(lane>>4)*4+reg ----
    unsigned short* C = Cp + (size_t)z * sC;
#pragma unroll
    for (int i = 0; i < 8; i++)
#pragma unroll
        for (int j = 0; j < 4; j++)
#pragma unroll
            for (int r = 0; r < 4; r++) {
                int m = tm + wr * 128 + i * 16 + lq * 4 + r;
                int n = tn + wc * 64 + j * 16 + lh;
                float v = acc[i][j][r] * scale;
                size_t idx = (size_t)m * N + n;
                if constexpr (ACC) C[idx] = f2bf(bf2f(C[idx]) + v);
                else               C[idx] = f2bf(v);
            }
}

// =====================================================================
// Row softmax, in place, bf16 rows of length 2048. One block per row.
// =====================================================================
__global__ __launch_bounds__(256)
void softmax_rows(unsigned short* __restrict__ P)
{
    const size_t row = blockIdx.x;
    unsigned short* p = P + row * 2048;
    const int t = threadIdx.x, lane = t & 63, wave = t >> 6;

    ushort8 u = *(const ushort8*)(p + t * 8);
    float v[8];
    float mx = -1e30f;
#pragma unroll
    for (int j = 0; j < 8; j++) { v[j] = bf2f(u[j]); mx = fmaxf(mx, v[j]); }
#pragma unroll
    for (int o = 32; o; o >>= 1) mx = fmaxf(mx, __shfl_xor(mx, o));

    __shared__ float red[8];
    if (lane == 0) red[wave] = mx;
    __syncthreads();
    mx = fmaxf(fmaxf(red[0], red[1]), fmaxf(red[2], red[3]));

    float s = 0.f;
#pragma unroll
    for (int j = 0; j < 8; j++) { v[j] = __expf(v[j] - mx); s += v[j]; }
#pragma unroll
    for (int o = 32; o; o >>= 1) s += __shfl_xor(s, o);
    if (lane == 0) red[4 + wave] = s;
    __syncthreads();
    float inv = 1.0f / (red[4] + red[5] + red[6] + red[7]);

    ushort8 o8;
#pragma unroll
    for (int j = 0; j < 8; j++) o8[j] = f2bf(v[j] * inv);
    *(ushort8*)(p + t * 8) = o8;
}

// =====================================================================
// x = 0.5*outs(bf16) + main_f(fp32); LayerNorm; partial max over 64 rows.
// =====================================================================
__global__ __launch_bounds__(256)
void ln_max_partial(const unsigned short* __restrict__ outs,
                    const float* __restrict__ mainf,
                    const float* __restrict__ gamma,
                    const float* __restrict__ beta,
                    float* __restrict__ partial)
{
    const int bx = blockIdx.x;
    const int b = bx >> 5, rc = bx & 31;
    const int t = threadIdx.x, lane = t & 63, wave = t >> 6;

    float g[16], be[16];
#pragma unroll
    for (int j = 0; j < 16; j++) { int d = j * 64 + lane; g[j] = gamma[d]; be[j] = beta[d]; }

    float rmax[16];
#pragma unroll
    for (int j = 0; j < 16; j++) rmax[j] = -1e30f;

    for (int rr = 0; rr < 16; rr++) {
        int l = rc * 64 + wave * 16 + rr;
        size_t base = ((size_t)b * 2048 + l) * 1024;
        float x[16], s = 0.f, s2 = 0.f;
#pragma unroll
        for (int j = 0; j < 16; j++) {
            int d = j * 64 + lane;
            float xv = 0.5f * bf2f(outs[base + d]) + mainf[base + d];
            x[j] = xv; s += xv; s2 += xv * xv;
        }
#pragma unroll
        for (int o = 32; o; o >>= 1) { s += __shfl_xor(s, o); s2 += __shfl_xor(s2, o); }
        float mu   = s * (1.f / 1024.f);
        float var  = s2 * (1.f / 1024.f) - mu * mu;
        float rstd = rsqrtf(var + 1e-5f);
#pragma unroll
        for (int j = 0; j < 16; j++) {
            float f = (x[j] - mu) * rstd * g[j] + be[j];
            rmax[j] = fmaxf(rmax[j], f);
        }
    }

    __shared__ float sm[4][1024];
#pragma unroll
    for (int j = 0; j < 16; j++) sm[wave][j * 64 + lane] = rmax[j];
    __syncthreads();
    for (int d = t; d < 1024; d += 256) {
        float m = fmaxf(fmaxf(sm[0][d], sm[1][d]), fmaxf(sm[2][d], sm[3][d]));
        partial[((size_t)b * 32 + rc) * 1024 + d] = m;
    }
}

__global__ __launch_bounds__(256)
void reduce_max_final(const float* __restrict__ partial, float* __restrict__ out)
{
    int i = blockIdx.x * 256 + threadIdx.x;
    if (i >= 8192) return;
    int b = i >> 10, d = i & 1023;
    const float* p = partial + (size_t)b * 32 * 1024 + d;
    float m = -1e30f;
#pragma unroll
    for (int rc = 0; rc < 32; rc++) m = fmaxf(m, p[(size_t)rc * 1024]);
    out[i] = m;
}

__global__ void ws_report(float* out, float v)
{
    int i = blockIdx.x * 256 + threadIdx.x;
    if (i < 8192) out[i] = v;
}

// =====================================================================
extern "C" void kernel_launch(void* const* d_in, const int* in_sizes, int n_in,
                              void* d_out, int out_size, void* d_ws, size_t ws_size,
                              hipStream_t stream)
{
    const float* mainf = (const float*)d_in[0];
    const float* cof1  = (const float*)d_in[1];
    const float* cof2  = (const float*)d_in[2];
    const float* Wq    = (const float*)d_in[3];
    const float* Wk1   = (const float*)d_in[4];
    const float* Wk2   = (const float*)d_in[5];
    const float* Wv1   = (const float*)d_in[6];
    const float* Wv2   = (const float*)d_in[7];
    const float* gamma = (const float*)d_in[8];
    const float* beta  = (const float*)d_in[9];
    float* out = (float*)d_out;

    const size_t NEED = 256ull << 20;
    if (ws_size < NEED) {
        ws_report<<<dim3(32), dim3(256), 0, stream>>>(out, (float)ws_size);
        return;
    }

    // ---- workspace plan (256 MiB, aliased) ----
    char* ws = (char*)d_ws;
    unsigned short* mainb = (unsigned short*)(ws);
    unsigned short* co1b  = (unsigned short*)(ws + (32ull  << 20));
    unsigned short* co2b  = (unsigned short*)(ws + (64ull  << 20));
    unsigned short* q     = (unsigned short*)(ws + (96ull  << 20));
    unsigned short* k1    = (unsigned short*)(ws + (128ull << 20));
    unsigned short* v1t   = (unsigned short*)(ws + (160ull << 20));
    unsigned short* P     = (unsigned short*)(ws + (192ull << 20));
    unsigned short* k2    = mainb;          // alias (mainb dead after q)
    unsigned short* v2t   = co1b;           // alias (co1b dead after v1t/k1)
    unsigned short* outs  = co2b;           // alias (co2b dead after k2/v2t)
    float*          part  = (float*)(ws + (96ull << 20)); // alias q (dead after QK2)

    dim3 blk(256);
    const long long LD = 2097152;    // L*D
    const long long LL = 4194304;    // L*L
    const float qk_scale = 0.03125f; // 1/sqrt(1024)

    // ---- fp32 -> bf16 bulk convert ----
    conv3_f32_bf16<<<dim3(2048, 3), blk, 0, stream>>>(mainf, cof1, cof2, mainb);

    // ---- projections: A bf16 (gld_lds), B = weight fp32 (reg-staged) ----
    // q/k: [16384 x 1024], K=1024 -> nbx=64, nby=4, 256 blocks
    gemm256<0, 1, 0><<<dim3(256), dim3(512), 0, stream>>>(mainb, Wq,  q,  1024, 1024, 0, 0, 0, 1.0f, 64, 4, 256);
    gemm256<0, 1, 0><<<dim3(256), dim3(512), 0, stream>>>(co1b,  Wk1, k1, 1024, 1024, 0, 0, 0, 1.0f, 64, 4, 256);
    gemm256<0, 1, 0><<<dim3(256), dim3(512), 0, stream>>>(co2b,  Wk2, k2, 1024, 1024, 0, 0, 0, 1.0f, 64, 4, 256);
    // vt[b][e][l]: A = Wv fp32 [1024x1024], Bt = co_b bf16; per-z 4x8 tiles, 8 z
    gemm256<1, 0, 0><<<dim3(256), dim3(512), 0, stream>>>(Wv1, co1b, v1t, 2048, 1024, 0, LD, LD, 1.0f, 4, 8, 32);
    gemm256<1, 0, 0><<<dim3(256), dim3(512), 0, stream>>>(Wv2, co2b, v2t, 2048, 1024, 0, LD, LD, 1.0f, 4, 8, 32);

    // ---- path 1 ----
    gemm256<0, 0, 0><<<dim3(512), dim3(512), 0, stream>>>(q, k1, P, 2048, 1024, LD, LD, LL, qk_scale, 8, 8, 64);
    softmax_rows<<<dim3(16384), blk, 0, stream>>>(P);
    gemm256<0, 0, 0><<<dim3(256), dim3(512), 0, stream>>>(P, v1t, outs, 1024, 2048, LL, LD, LD, 1.0f, 8, 4, 32);

    // ---- path 2 ----
    gemm256<0, 0, 0><<<dim3(512), dim3(512), 0, stream>>>(q, k2, P, 2048, 1024, LD, LD, LL, qk_scale, 8, 8, 64);
    softmax_rows<<<dim3(16384), blk, 0, stream>>>(P);
    gemm256<0, 0, 1><<<dim3(256), dim3(512), 0, stream>>>(P, v2t, outs, 1024, 2048, LL, LD, LD, 1.0f, 8, 4, 32);

    // ---- residual + LN + max over sequence ----
    ln_max_partial<<<dim3(256), blk, 0, stream>>>(outs, mainf, gamma, beta, part);
    reduce_max_final<<<dim3(32), blk, 0, stream>>>(part, out);
}

// Round 5
// 685.150 us; speedup vs baseline: 1.5934x; 1.1448x over previous
//
#include <hip/hip_runtime.h>

#define DEVI __device__ __forceinline__

typedef __attribute__((ext_vector_type(4))) float   f32x4;
typedef __attribute__((ext_vector_type(8))) short   short8;
typedef __attribute__((ext_vector_type(8))) unsigned short ushort8;

DEVI float bf2f(unsigned short u) {
    unsigned int x = ((unsigned int)u) << 16;
    float f; __builtin_memcpy(&f, &x, 4); return f;
}
DEVI unsigned short f2bf(float f) {
    unsigned int x; __builtin_memcpy(&x, &x, 0), __builtin_memcpy(&x, &f, 4);
    unsigned int r = x + 0x7FFFu + ((x >> 16) & 1u);
    return (unsigned short)(r >> 16);
}

DEVI f32x4 mfma_bf16(short8 a, short8 b, f32x4 c) {
    return __builtin_amdgcn_mfma_f32_16x16x32_bf16(a, b, c, 0, 0, 0);
}

DEVI void gld_lds16(const void* g, void* l) {
    __builtin_amdgcn_global_load_lds(
        (const __attribute__((address_space(1))) void*)g,
        (__attribute__((address_space(3))) void*)l, 16, 0, 0);
}

// =====================================================================
// fp32 -> bf16 bulk converts
// =====================================================================
__global__ __launch_bounds__(256)
void conv3_f32_bf16(const float* __restrict__ a, const float* __restrict__ b,
                    const float* __restrict__ c, unsigned short* __restrict__ o)
{
    const float* src = (blockIdx.y == 0) ? a : (blockIdx.y == 1 ? b : c);
    unsigned short* dst = o + (size_t)blockIdx.y * 16777216ull;
    const size_t step = (size_t)gridDim.x * 256 * 8;
    for (size_t i = ((size_t)blockIdx.x * 256 + threadIdx.x) * 8; i < 16777216ull; i += step) {
        f32x4 f0 = *(const f32x4*)(src + i);
        f32x4 f1 = *(const f32x4*)(src + i + 4);
        ushort8 h;
#pragma unroll
        for (int e = 0; e < 4; e++) { h[e] = f2bf(f0[e]); h[e + 4] = f2bf(f1[e]); }
        *(ushort8*)(dst + i) = h;
    }
}

__global__ __launch_bounds__(256)
void convw_f32_bf16(const float* __restrict__ w0, const float* __restrict__ w1,
                    const float* __restrict__ w2, const float* __restrict__ w3,
                    const float* __restrict__ w4, unsigned short* __restrict__ o)
{
    const float* srcs[5] = {w0, w1, w2, w3, w4};
    const float* src = srcs[blockIdx.y];
    unsigned short* dst = o + (size_t)blockIdx.y * 1048576ull;
    const size_t step = (size_t)gridDim.x * 256 * 8;
    for (size_t i = ((size_t)blockIdx.x * 256 + threadIdx.x) * 8; i < 1048576ull; i += step) {
        f32x4 f0 = *(const f32x4*)(src + i);
        f32x4 f1 = *(const f32x4*)(src + i + 4);
        ushort8 h;
#pragma unroll
        for (int e = 0; e < 4; e++) { h[e] = f2bf(f0[e]); h[e + 4] = f2bf(f1[e]); }
        *(ushort8*)(dst + i) = h;
    }
}

// =====================================================================
// GEMM 256x256, BK=64, 8 waves, 8-phase schedule (T2+T3+T4+T5), all bf16.
// C[m,n] = scale * sum_k A[m,k]*Bt[n,k].   Bt is [N][K] row-major.
// Per K-tile: 4 phases (quads of 2 i-values); phase reads: P1 = B all (8
// ds_read_b128) + A quad0 (4); P2-4 = A quad (4). Stage ledger (per tile m):
//   P1: A-strips 2,3 of tile m+1  (regions died at tile m-1 phases 3,4)
//   P2: B-half0 of tile m+2       (B of buf died at phase 1)
//   P3: B-half1 of tile m+2
//   P4: A-strips 0,1 of tile m+2  (strips died at phases 1,2)
// One counted wait per tile: vmcnt(8) at phase 1 (= 4 ticks x 2 glds in
// flight); vmcnt(0) only for the last tile. Raw s_barrier (no vmcnt drain).
// LDS rows 64 bf16 (128 B), T2 swizzle granule ^= (row&7), both-sides.
// =====================================================================
template<int ACC>
__global__ __launch_bounds__(512, 1)
void gemm8p(const unsigned short* __restrict__ Ap, const unsigned short* __restrict__ Bp,
            unsigned short* __restrict__ Cp,
            int N, int K, long long sA, long long sB, long long sC,
            float scale, int nbx, int nby, int nwg_z)
{
    __shared__ unsigned short As[2][256][64];   // 64 KB
    __shared__ unsigned short Bs[2][256][64];   // 64 KB

    const int t    = threadIdx.x;
    const int lane = t & 63, wave = t >> 6;
    const int wr   = wave >> 2, wc = wave & 3;   // 2 x 4 wave grid
    const int lh   = lane & 15, lq = lane >> 4;
    const int l8   = lh & 7;

    // ---- block swizzle: XCD bijective chunk, then group-M ----
    const int total = (int)gridDim.x;            // % 8 == 0 for all our grids
    const int lid   = blockIdx.x;
    const int q0    = total >> 3;
    const int swz   = (lid & 7) * q0 + (lid >> 3);
    const int z     = swz / nwg_z;
    const int id2   = swz - z * nwg_z;
    const int GRP   = 8;
    const int gsz   = GRP * nby;
    const int grp   = id2 / gsz, loc = id2 - grp * gsz;
    int gm = nbx - grp * GRP; gm = (gm > GRP) ? GRP : gm;
    const int bx = grp * GRP + loc % gm;
    const int by = loc / gm;
    const int tm = bx << 8, tn = by << 8;

    const int srow  = t >> 3;        // 0..63
    const int sslot = t & 7;
    const int rsw   = srow & 7;

    const unsigned short* A = Ap + (size_t)z * sA;
    const unsigned short* B = Bp + (size_t)z * sB;

    f32x4 acc[8][4];
#pragma unroll
    for (int i = 0; i < 8; i++)
#pragma unroll
        for (int j = 0; j < 4; j++) acc[i][j] = f32x4{0.f, 0.f, 0.f, 0.f};

    const int NT = K >> 6;

    // stage units: B-half h = rows 128h..128h+127 (2 glds);
    // A-strip s = rows {32s..32s+31} U {128+32s..128+32s+31} (1 gld).
    auto stageBhalf = [&](int buf, int kt, int h) {
        const int k0 = kt << 6;
#pragma unroll
        for (int p = 0; p < 2; p++) {
            int row = h * 128 + p * 64 + srow;
            gld_lds16(B + (size_t)(tn + row) * K + k0 + ((sslot ^ rsw) << 3),
                      &Bs[buf][row][sslot << 3]);
        }
    };
    auto stageAstrip = [&](int buf, int kt, int s) {
        const int k0 = kt << 6;
        int row = s * 32 + (srow & 31) + ((srow >> 5) << 7);
        gld_lds16(A + (size_t)(tm + row) * K + k0 + ((sslot ^ rsw) << 3),
                  &As[buf][row][sslot << 3]);
    };
    auto rdA = [&](int buf, int i, int kk) -> short8 {
        return *(const short8*)&As[buf][wr * 128 + i * 16 + lh][((((kk << 2) | lq)) ^ l8) << 3];
    };
    auto rdB = [&](int buf, int j, int kk) -> short8 {
        return *(const short8*)&Bs[buf][wc * 64 + j * 16 + lh][((((kk << 2) | lq)) ^ l8) << 3];
    };

    // ---- prologue: T0 fully (8 glds), T1 partially (B + strips0,1 = 6) ----
    stageBhalf(0, 0, 0); stageBhalf(0, 0, 1);
    stageAstrip(0, 0, 0); stageAstrip(0, 0, 1); stageAstrip(0, 0, 2); stageAstrip(0, 0, 3);
    stageBhalf(1, 1, 0); stageBhalf(1, 1, 1);
    stageAstrip(1, 1, 0); stageAstrip(1, 1, 1);

    for (int m = 0; m < NT; m++) {
        const int cur = m & 1;
        short8 bq[4][2];

        // ================= phase 1 (quad 0) =================
        if (m + 1 < NT) { stageAstrip(cur ^ 1, m + 1, 2); stageAstrip(cur ^ 1, m + 1, 3); }
        if (m == NT - 1) { asm volatile("s_waitcnt vmcnt(0)" ::: "memory"); }
        else             { asm volatile("s_waitcnt vmcnt(8)" ::: "memory"); }
        __builtin_amdgcn_sched_barrier(0);
        __builtin_amdgcn_s_barrier();
        {
#pragma unroll
            for (int j = 0; j < 4; j++) { bq[j][0] = rdB(cur, j, 0); bq[j][1] = rdB(cur, j, 1); }
            short8 a00 = rdA(cur, 0, 0), a01 = rdA(cur, 0, 1);
            short8 a10 = rdA(cur, 1, 0), a11 = rdA(cur, 1, 1);
            asm volatile("s_waitcnt lgkmcnt(0)" ::: "memory");
            __builtin_amdgcn_s_setprio(1);
#pragma unroll
            for (int j = 0; j < 4; j++) {
                acc[0][j] = mfma_bf16(a00, bq[j][0], acc[0][j]);
                acc[0][j] = mfma_bf16(a01, bq[j][1], acc[0][j]);
                acc[1][j] = mfma_bf16(a10, bq[j][0], acc[1][j]);
                acc[1][j] = mfma_bf16(a11, bq[j][1], acc[1][j]);
            }
            __builtin_amdgcn_s_setprio(0);
            __builtin_amdgcn_s_barrier();
        }
        // ================= phase 2 (quad 1) =================
        {
            short8 a00 = rdA(cur, 2, 0), a01 = rdA(cur, 2, 1);
            short8 a10 = rdA(cur, 3, 0), a11 = rdA(cur, 3, 1);
            if (m + 2 < NT) stageBhalf(cur, m + 2, 0);
            __builtin_amdgcn_s_barrier();
            asm volatile("s_waitcnt lgkmcnt(0)" ::: "memory");
            __builtin_amdgcn_s_setprio(1);
#pragma unroll
            for (int j = 0; j < 4; j++) {
                acc[2][j] = mfma_bf16(a00, bq[j][0], acc[2][j]);
                acc[2][j] = mfma_bf16(a01, bq[j][1], acc[2][j]);
                acc[3][j] = mfma_bf16(a10, bq[j][0], acc[3][j]);
                acc[3][j] = mfma_bf16(a11, bq[j][1], acc[3][j]);
            }
            __builtin_amdgcn_s_setprio(0);
            __builtin_amdgcn_s_barrier();
        }
        // ================= phase 3 (quad 2) =================
        {
            short8 a00 = rdA(cur, 4, 0), a01 = rdA(cur, 4, 1);
            short8 a10 = rdA(cur, 5, 0), a11 = rdA(cur, 5, 1);
            if (m + 2 < NT) stageBhalf(cur, m + 2, 1);
            __builtin_amdgcn_s_barrier();
            asm volatile("s_waitcnt lgkmcnt(0)" ::: "memory");
            __builtin_amdgcn_s_setprio(1);
#pragma unroll
            for (int j = 0; j < 4; j++) {
                acc[4][j] = mfma_bf16(a00, bq[j][0], acc[4][j]);
                acc[4][j] = mfma_bf16(a01, bq[j][1], acc[4][j]);
                acc[5][j] = mfma_bf16(a10, bq[j][0], acc[5][j]);
                acc[5][j] = mfma_bf16(a11, bq[j][1], acc[5][j]);
            }
            __builtin_amdgcn_s_setprio(0);
            __builtin_amdgcn_s_barrier();
        }
        // ================= phase 4 (quad 3) =================
        {
            short8 a00 = rdA(cur, 6, 0), a01 = rdA(cur, 6, 1);
            short8 a10 = rdA(cur, 7, 0), a11 = rdA(cur, 7, 1);
            if (m + 2 < NT) { stageAstrip(cur, m + 2, 0); stageAstrip(cur, m + 2, 1); }
            __builtin_amdgcn_s_barrier();
            asm volatile("s_waitcnt lgkmcnt(0)" ::: "memory");
            __builtin_amdgcn_s_setprio(1);
#pragma unroll
            for (int j = 0; j < 4; j++) {
                acc[6][j] = mfma_bf16(a00, bq[j][0], acc[6][j]);
                acc[6][j] = mfma_bf16(a01, bq[j][1], acc[6][j]);
                acc[7][j] = mfma_bf16(a10, bq[j][0], acc[7][j]);
                acc[7][j] = mfma_bf16(a11, bq[j][1], acc[7][j]);
            }
            __builtin_amdgcn_s_setprio(0);
            __builtin_amdgcn_s_barrier();
        }
    }

    // ---- epilogue: C/D frag col=lane&15, row=(lane>>4)*4+reg ----
    unsigned short* C = Cp + (size_t)z * sC;
#pragma unroll
    for (int i = 0; i < 8; i++)
#pragma unroll
        for (int j = 0; j < 4; j++)
#pragma unroll
            for (int r = 0; r < 4; r++) {
                int mm = tm + wr * 128 + i * 16 + lq * 4 + r;
                int nn = tn + wc * 64 + j * 16 + lh;
                float v = acc[i][j][r] * scale;
                size_t idx = (size_t)mm * N + nn;
                if constexpr (ACC) C[idx] = f2bf(bf2f(C[idx]) + v);
                else               C[idx] = f2bf(v);
            }
}

// =====================================================================
// Row softmax, in place, bf16 rows of length 2048. One block per row.
// =====================================================================
__global__ __launch_bounds__(256)
void softmax_rows(unsigned short* __restrict__ P)
{
    const size_t row = blockIdx.x;
    unsigned short* p = P + row * 2048;
    const int t = threadIdx.x, lane = t & 63, wave = t >> 6;

    ushort8 u = *(const ushort8*)(p + t * 8);
    float v[8];
    float mx = -1e30f;
#pragma unroll
    for (int j = 0; j < 8; j++) { v[j] = bf2f(u[j]); mx = fmaxf(mx, v[j]); }
#pragma unroll
    for (int o = 32; o; o >>= 1) mx = fmaxf(mx, __shfl_xor(mx, o));

    __shared__ float red[8];
    if (lane == 0) red[wave] = mx;
    __syncthreads();
    mx = fmaxf(fmaxf(red[0], red[1]), fmaxf(red[2], red[3]));

    float s = 0.f;
#pragma unroll
    for (int j = 0; j < 8; j++) { v[j] = __expf(v[j] - mx); s += v[j]; }
#pragma unroll
    for (int o = 32; o; o >>= 1) s += __shfl_xor(s, o);
    if (lane == 0) red[4 + wave] = s;
    __syncthreads();
    float inv = 1.0f / (red[4] + red[5] + red[6] + red[7]);

    ushort8 o8;
#pragma unroll
    for (int j = 0; j < 8; j++) o8[j] = f2bf(v[j] * inv);
    *(ushort8*)(p + t * 8) = o8;
}

// =====================================================================
// x = 0.5*outs(bf16) + main_f(fp32); LayerNorm; partial max over 64 rows.
// =====================================================================
__global__ __launch_bounds__(256)
void ln_max_partial(const unsigned short* __restrict__ outs,
                    const float* __restrict__ mainf,
                    const float* __restrict__ gamma,
                    const float* __restrict__ beta,
                    float* __restrict__ partial)
{
    const int bx = blockIdx.x;
    const int b = bx >> 5, rc = bx & 31;
    const int t = threadIdx.x, lane = t & 63, wave = t >> 6;

    float g[16], be[16];
#pragma unroll
    for (int j = 0; j < 16; j++) { int d = j * 64 + lane; g[j] = gamma[d]; be[j] = beta[d]; }

    float rmax[16];
#pragma unroll
    for (int j = 0; j < 16; j++) rmax[j] = -1e30f;

    for (int rr = 0; rr < 16; rr++) {
        int l = rc * 64 + wave * 16 + rr;
        size_t base = ((size_t)b * 2048 + l) * 1024;
        float x[16], s = 0.f, s2 = 0.f;
#pragma unroll
        for (int j = 0; j < 16; j++) {
            int d = j * 64 + lane;
            float xv = 0.5f * bf2f(outs[base + d]) + mainf[base + d];
            x[j] = xv; s += xv; s2 += xv * xv;
        }
#pragma unroll
        for (int o = 32; o; o >>= 1) { s += __shfl_xor(s, o); s2 += __shfl_xor(s2, o); }
        float mu   = s * (1.f / 1024.f);
        float var  = s2 * (1.f / 1024.f) - mu * mu;
        float rstd = rsqrtf(var + 1e-5f);
#pragma unroll
        for (int j = 0; j < 16; j++) {
            float f = (x[j] - mu) * rstd * g[j] + be[j];
            rmax[j] = fmaxf(rmax[j], f);
        }
    }

    __shared__ float sm[4][1024];
#pragma unroll
    for (int j = 0; j < 16; j++) sm[wave][j * 64 + lane] = rmax[j];
    __syncthreads();
    for (int d = t; d < 1024; d += 256) {
        float m = fmaxf(fmaxf(sm[0][d], sm[1][d]), fmaxf(sm[2][d], sm[3][d]));
        partial[((size_t)b * 32 + rc) * 1024 + d] = m;
    }
}

__global__ __launch_bounds__(256)
void reduce_max_final(const float* __restrict__ partial, float* __restrict__ out)
{
    int i = blockIdx.x * 256 + threadIdx.x;
    if (i >= 8192) return;
    int b = i >> 10, d = i & 1023;
    const float* p = partial + (size_t)b * 32 * 1024 + d;
    float m = -1e30f;
#pragma unroll
    for (int rc = 0; rc < 32; rc++) m = fmaxf(m, p[(size_t)rc * 1024]);
    out[i] = m;
}

__global__ void ws_report(float* out, float v)
{
    int i = blockIdx.x * 256 + threadIdx.x;
    if (i < 8192) out[i] = v;
}

// =====================================================================
extern "C" void kernel_launch(void* const* d_in, const int* in_sizes, int n_in,
                              void* d_out, int out_size, void* d_ws, size_t ws_size,
                              hipStream_t stream)
{
    const float* mainf = (const float*)d_in[0];
    const float* cof1  = (const float*)d_in[1];
    const float* cof2  = (const float*)d_in[2];
    const float* Wq    = (const float*)d_in[3];
    const float* Wk1   = (const float*)d_in[4];
    const float* Wk2   = (const float*)d_in[5];
    const float* Wv1   = (const float*)d_in[6];
    const float* Wv2   = (const float*)d_in[7];
    const float* gamma = (const float*)d_in[8];
    const float* beta  = (const float*)d_in[9];
    float* out = (float*)d_out;

    const size_t NEED = 256ull << 20;
    if (ws_size < NEED) {
        ws_report<<<dim3(32), dim3(256), 0, stream>>>(out, (float)ws_size);
        return;
    }

    // ---- workspace plan (256 MiB, aliased) ----
    // 0-32 mainb->k2; 32-64 co1b->v2t; 64-96 co2b->outs; 96-128 q->part;
    // 128-160 k1; 160-192 v1t; 192-256 P (first 10 MiB = bf16 weights until QK1)
    char* ws = (char*)d_ws;
    unsigned short* mainb = (unsigned short*)(ws);
    unsigned short* co1b  = (unsigned short*)(ws + (32ull  << 20));
    unsigned short* co2b  = (unsigned short*)(ws + (64ull  << 20));
    unsigned short* q     = (unsigned short*)(ws + (96ull  << 20));
    unsigned short* k1    = (unsigned short*)(ws + (128ull << 20));
    unsigned short* v1t   = (unsigned short*)(ws + (160ull << 20));
    unsigned short* P     = (unsigned short*)(ws + (192ull << 20));
    unsigned short* wb    = P;              // 5 x 1 Mi-elem bf16 weights (dead at QK1)
    unsigned short* k2    = mainb;          // alias (mainb dead after q)
    unsigned short* v2t   = co1b;           // alias (co1b dead after k1/v1t)
    unsigned short* outs  = co2b;           // alias (co2b dead after k2/v2t)
    float*          part  = (float*)(ws + (96ull << 20)); // alias q (dead after QK2)

    dim3 blk(256);
    const long long LD = 2097152;    // L*D
    const long long LL = 4194304;    // L*L
    const float qk_scale = 0.03125f; // 1/sqrt(1024)

    // ---- fp32 -> bf16 converts (activations + weights) ----
    conv3_f32_bf16<<<dim3(2048, 3), blk, 0, stream>>>(mainf, cof1, cof2, mainb);
    convw_f32_bf16<<<dim3(128, 5), blk, 0, stream>>>(Wq, Wk1, Wk2, Wv1, Wv2, wb);

    unsigned short* Wqb  = wb;
    unsigned short* Wk1b = wb + 1048576ull;
    unsigned short* Wk2b = wb + 2097152ull;
    unsigned short* Wv1b = wb + 3145728ull;
    unsigned short* Wv2b = wb + 4194304ull;

    // ---- projections (all bf16, 8-phase) ----
    gemm8p<0><<<dim3(256), dim3(512), 0, stream>>>(mainb, Wqb,  q,  1024, 1024, 0, 0, 0, 1.0f, 64, 4, 256);
    gemm8p<0><<<dim3(256), dim3(512), 0, stream>>>(co1b,  Wk1b, k1, 1024, 1024, 0, 0, 0, 1.0f, 64, 4, 256);
    gemm8p<0><<<dim3(256), dim3(512), 0, stream>>>(co2b,  Wk2b, k2, 1024, 1024, 0, 0, 0, 1.0f, 64, 4, 256);
    // vt[b][e][l]: A = Wv [1024x1024], Bt = co_b; per-z 4x8 tiles, 8 z
    gemm8p<0><<<dim3(256), dim3(512), 0, stream>>>(Wv1b, co1b, v1t, 2048, 1024, 0, LD, LD, 1.0f, 4, 8, 32);
    gemm8p<0><<<dim3(256), dim3(512), 0, stream>>>(Wv2b, co2b, v2t, 2048, 1024, 0, LD, LD, 1.0f, 4, 8, 32);

    // ---- path 1 ----
    gemm8p<0><<<dim3(512), dim3(512), 0, stream>>>(q, k1, P, 2048, 1024, LD, LD, LL, qk_scale, 8, 8, 64);
    softmax_rows<<<dim3(16384), blk, 0, stream>>>(P);
    gemm8p<0><<<dim3(256), dim3(512), 0, stream>>>(P, v1t, outs, 1024, 2048, LL, LD, LD, 1.0f, 8, 4, 32);

    // ---- path 2 ----
    gemm8p<0><<<dim3(512), dim3(512), 0, stream>>>(q, k2, P, 2048, 1024, LD, LD, LL, qk_scale, 8, 8, 64);
    softmax_rows<<<dim3(16384), blk, 0, stream>>>(P);
    gemm8p<1><<<dim3(256), dim3(512), 0, stream>>>(P, v2t, outs, 1024, 2048, LL, LD, LD, 1.0f, 8, 4, 32);

    // ---- residual + LN + max over sequence ----
    ln_max_partial<<<dim3(256), blk, 0, stream>>>(outs, mainf, gamma, beta, part);
    reduce_max_final<<<dim3(32), blk, 0, stream>>>(part, out);
}